// Round 16
// baseline (76.811 us; speedup 1.0000x reference)
//
#include <hip/hip_runtime.h>
#include <math.h>

#define NSEQ 256
#define SLEN 48
#define DIN  64
#define NCH  8
#define LOG2E 1.4426950408889634f

typedef _Float16 half8  __attribute__((ext_vector_type(8)));
typedef __fp16   fp16x2 __attribute__((ext_vector_type(2)));
typedef float    f32x4  __attribute__((ext_vector_type(4)));

union U8 { _Float16 h[8]; uint4 u; unsigned int w[4]; half8 v; };
union U2 { _Float16 h[4]; uint2 u; };
union UPK { fp16x2 f; unsigned int i; };

// ---------------- K1: mask bits + out[:,127] ----------------
__global__ __launch_bounds__(256) void mask_k(const int* __restrict__ mask,
                                              unsigned long long* __restrict__ mask64,
                                              float* __restrict__ out) {
    int wid  = (blockIdx.x * 256 + threadIdx.x) >> 6;
    int lane = threadIdx.x & 63;
    if (wid >= NSEQ) return;
    int mv = (lane < SLEN) ? mask[wid * SLEN + lane] : 0;
    unsigned long long b = __ballot(mv != 0);
    if (lane == 0) { mask64[wid] = b; out[wid * 128 + 127] = b ? 1.f : 0.f; }
}

// ---------------- K2: W -> f16 fragment layout ----------------
// perm=0 (W1, A-op of L1):  row = 32kt + 8g + e
// perm=1 (W2, B-op of L2):  row = 32kt + 16(e>>2) + 4g + (e&3)   [k-axis perm π]
__global__ __launch_bounds__(256) void wprep_k(const float* __restrict__ W,
                                               unsigned short* __restrict__ Wf,
                                               float scale, int perm) {
    __shared__ float wl[DIN * DIN];
    int d = blockIdx.x;
    const float* src = W + (size_t)d * DIN * DIN;
    for (int k = threadIdx.x; k < DIN * DIN / 4; k += 256)
        ((float4*)wl)[k] = ((const float4*)src)[k];
    __syncthreads();
    for (int rr = 0; rr < 2; ++rr) {
        int idx = threadIdx.x * 2 + rr;
        int fid = idx >> 6, l = idx & 63;
        int mt = fid >> 1, kt = fid & 1, g = l >> 4, c = l & 15;
        U8 t;
        #pragma unroll
        for (int e = 0; e < 8; ++e) {
            int row = perm ? (32 * kt + 16 * (e >> 2) + 4 * g + (e & 3))
                           : (32 * kt + 8 * g + e);
            t.h[e] = (_Float16)(wl[row * DIN + (16 * mt + c)] * scale);
        }
        *(uint4*)(Wf + ((size_t)(d * 8 + fid) * 64 + l) * 8) = t.u;
    }
}

// ---------------- K3a: embedding -> f16, row-major, chunk-swizzled ----------
__global__ __launch_bounds__(256) void embed_k(const float* __restrict__ values,
                                               const float* __restrict__ times,
                                               const float* __restrict__ omega,
                                               const float* __restrict__ alpha,
                                               unsigned short* __restrict__ zh) {
    int id = blockIdx.x * 256 + threadIdx.x;
    int ch = id & 7, ns = id >> 3;
    if (ns >= NSEQ * SLEN) return;
    int s = ns % SLEN;
    float t = times[ns];
    U8 o;
    #pragma unroll
    for (int e = 0; e < 8; ++e) {
        int i = ch * 8 + e;
        float r;
        if (i == 0)       r = omega[0] * t + alpha[0];
        else if (i == 63) r = values[ns];
        else              r = __sinf(t * omega[i] + alpha[i]);
        o.h[e] = (_Float16)r;
    }
    int csw = ch ^ (s & 7);
    *(uint4*)(zh + (size_t)ns * 64 + csw * 8) = o.u;
}

// ---------------- K3b: transposed embedding zhT[n][j][s], row stride 56 -----
__global__ __launch_bounds__(256) void embedT_k(const float* __restrict__ values,
                                                const float* __restrict__ times,
                                                const float* __restrict__ omega,
                                                const float* __restrict__ alpha,
                                                unsigned short* __restrict__ zhT) {
    int id = blockIdx.x * 256 + threadIdx.x;
    int unit = id & 511, n = id >> 9;
    int sc = unit >> 6;
    if (sc >= 6) return;
    int j = unit & 63;
    int s0 = sc * 8;
    const float* tp = times + n * SLEN + s0;
    float4 t0 = *(const float4*)tp, t1 = *(const float4*)(tp + 4);
    float tv[8] = {t0.x, t0.y, t0.z, t0.w, t1.x, t1.y, t1.z, t1.w};
    U8 o;
    if (j == 0) {
        float om = omega[0], al = alpha[0];
        #pragma unroll
        for (int e = 0; e < 8; ++e) o.h[e] = (_Float16)(om * tv[e] + al);
    } else if (j == 63) {
        const float* vp = values + n * SLEN + s0;
        float4 v0 = *(const float4*)vp, v1 = *(const float4*)(vp + 4);
        float vv[8] = {v0.x, v0.y, v0.z, v0.w, v1.x, v1.y, v1.z, v1.w};
        #pragma unroll
        for (int e = 0; e < 8; ++e) o.h[e] = (_Float16)vv[e];
    } else {
        float om = omega[j], al = alpha[j];
        #pragma unroll
        for (int e = 0; e < 8; ++e) o.h[e] = (_Float16)__sinf(tv[e] * om + al);
    }
    *(uint4*)(zhT + (size_t)n * 3584 + j * 56 + s0) = o.u;
}

// ---------------- K4: main fused kernel — L2-fit XCD remap + zf rotation ----
// 512-thread blocks, launch_bounds(512,2) = the proven no-spill point (cap
// 128, body ~108). Zero LDS/barriers. NEW vs r15:
// (a) XCD-aware remap: lin%8 = XCD (round-robin dispatch, m09); each XCD owns
//     2 d-octets (weights 0.26MB) x all n (3.25MB) = 3.5MB <= 4MB L2 -> reads
//     become L2 hits instead of L3 (~600cyc) after L2 thrash (r15 working set
//     was 5.3MB/XCD).
// (b) Rotated zf prefetch: unit n+1's 6 zf loads issue right after unit n's
//     L1 MFMAs consume zf — back-half (~3k cyc) hides the latency, 0 extra
//     registers (same zf regs, extended lifetime).
__global__ __launch_bounds__(512, 2) void filter_k(
    const unsigned short* __restrict__ zh,
    const unsigned short* __restrict__ zhT,
    const unsigned long long* __restrict__ mask64,
    const unsigned short* __restrict__ w1f, const unsigned short* __restrict__ w2f,
    const float* __restrict__ b1, const float* __restrict__ b2,
    float* __restrict__ out)
{
    const int tid = threadIdx.x;
    const int w = tid >> 6, lane = tid & 63;
    const int g = lane >> 4, c = lane & 15;

    // XCD-aware remap: 512 blocks; xcd = lin%8, slot = lin/8 (0..63)
    const int lin   = blockIdx.y * 32 + blockIdx.x;
    const int xcd   = lin & 7, slot = lin >> 3;
    const int octet = xcd * 2 + (slot & 1);     // 0..15 (2 octets per XCD)
    const int nchk  = slot >> 1;                // 0..31
    const int d = octet * 8 + w;
    if (d >= 127) return;                       // whole-wave exit; no barriers
    const int nb = nchk * NCH;

    // per-d constants (L2-resident, reused across 8 n's)
    half8 w1fr[8], w2fr[8];
    #pragma unroll
    for (int f = 0; f < 8; ++f) {
        w1fr[f] = *(const half8*)(w1f + ((size_t)(d * 8 + f) * 64 + lane) * 8);
        w2fr[f] = *(const half8*)(w2f + ((size_t)(d * 8 + f) * 64 + lane) * 8);
    }
    float4 b1q[4];
    #pragma unroll
    for (int hm = 0; hm < 4; ++hm)
        b1q[hm] = *(const float4*)(b1 + d * DIN + 16 * hm + 4 * g);
    float b2v[4];
    #pragma unroll
    for (int jt = 0; jt < 4; ++jt)
        b2v[jt] = b2[d * DIN + 16 * jt + c] * LOG2E;

    // hoisted global-address offsets (element units)
    int zoff[2][3];   // b128 frag reads: row s=16st+c, chunk (4kt+g)^(s&7)
    #pragma unroll
    for (int kt = 0; kt < 2; ++kt)
        #pragma unroll
        for (int st = 0; st < 3; ++st) {
            int s = 16 * st + c;
            zoff[kt][st] = s * 64 + (((4 * kt + g) ^ (s & 7)) << 3);
        }
    const int ztbase = c * 56 + 4 * g;   // zT: row j=16jt+c, s=16st+4g

    // ---- preload unit 0's zf + mask (rotation seed)
    half8 zf[2][3];
    unsigned long long mw;
    {
        const unsigned short* zl = zh + (size_t)nb * 3072;
        #pragma unroll
        for (int kt = 0; kt < 2; ++kt)
            #pragma unroll
            for (int st = 0; st < 3; ++st)
                zf[kt][st] = *(const half8*)(zl + zoff[kt][st]);
        mw = mask64[nb];
    }

    #pragma unroll 1
    for (int ni = 0; ni < NCH; ++ni) {
        const int n = nb + ni;
        const unsigned short* zt = zhT + (size_t)n * 3584;

        // mask -> additive bias per (st,r): s = 16st+4g+r; 0 or -16384
        // (must read mw BEFORE the rotation overwrites it)
        f32x4 binit[3];
        #pragma unroll
        for (int st = 0; st < 3; ++st)
            #pragma unroll
            for (int r = 0; r < 4; ++r)
                binit[st][r] = ((mw >> (16 * st + 4 * g + r)) & 1ull) ? 0.f : -16384.f;

        // ---- layer 1: H^T = W1^T x Z^T (zf preloaded)
        f32x4 aH[4][3];
        #pragma unroll
        for (int hm = 0; hm < 4; ++hm)
            #pragma unroll
            for (int st = 0; st < 3; ++st) {
                aH[hm][st] = (f32x4){b1q[hm].x, b1q[hm].y, b1q[hm].z, b1q[hm].w};
                #pragma unroll
                for (int kt = 0; kt < 2; ++kt)
                    aH[hm][st] = __builtin_amdgcn_mfma_f32_16x16x32_f16(
                        w1fr[hm * 2 + kt], zf[kt][st], aH[hm][st], 0, 0, 0);
            }

        // ---- rotation: zf consumed -> issue next unit's zf + mask now;
        // the entire back-half below hides the L2 latency.
        if (ni + 1 < NCH) {
            const unsigned short* zl = zh + (size_t)(n + 1) * 3072;
            #pragma unroll
            for (int kt = 0; kt < 2; ++kt)
                #pragma unroll
                for (int st = 0; st < 3; ++st)
                    zf[kt][st] = *(const half8*)(zl + zoff[kt][st]);
            mw = mask64[n + 1];
        }

        // relu -> packed f16 pairs (registers only)
        unsigned int pk[4][3][2];
        #pragma unroll
        for (int hm = 0; hm < 4; ++hm)
            #pragma unroll
            for (int st = 0; st < 3; ++st) {
                float r0 = fmaxf(aH[hm][st][0], 0.f), r1 = fmaxf(aH[hm][st][1], 0.f);
                float r2 = fmaxf(aH[hm][st][2], 0.f), r3 = fmaxf(aH[hm][st][3], 0.f);
                UPK a, b;
                a.f = __builtin_amdgcn_cvt_pkrtz(r0, r1);
                b.f = __builtin_amdgcn_cvt_pkrtz(r2, r3);
                pk[hm][st][0] = a.i;
                pk[hm][st][1] = b.i;
            }

        // ---- per-jt: L2 MFMA (k-permuted, A lane-local) + softmax + sum
        U2 zuc[3], zun[3];
        #pragma unroll
        for (int st = 0; st < 3; ++st)
            zuc[st].u = *(const uint2*)(zt + ztbase + st * 16);
        float part = 0.f;
        #pragma unroll
        for (int jt = 0; jt < 4; ++jt) {
            f32x4 aL3[3];
            #pragma unroll
            for (int st = 0; st < 3; ++st) {
                aL3[st] = binit[st] + b2v[jt];     // bias + mask fold at C-init
                #pragma unroll
                for (int kt = 0; kt < 2; ++kt) {
                    U8 hfu;
                    hfu.w[0] = pk[2 * kt + 0][st][0];
                    hfu.w[1] = pk[2 * kt + 0][st][1];
                    hfu.w[2] = pk[2 * kt + 1][st][0];
                    hfu.w[3] = pk[2 * kt + 1][st][1];
                    aL3[st] = __builtin_amdgcn_mfma_f32_16x16x32_f16(
                        hfu.v, w2fr[jt * 2 + kt], aL3[st], 0, 0, 0);
                }
            }
            if (jt < 3) {
                #pragma unroll
                for (int st = 0; st < 3; ++st)
                    zun[st].u = *(const uint2*)(zt + ztbase + (jt + 1) * 896 + st * 16);
            }
            float e[3][4];
            float den = 0.f;
            #pragma unroll
            for (int st = 0; st < 3; ++st)
                #pragma unroll
                for (int r = 0; r < 4; ++r) {
                    float v = exp2f(aL3[st][r]);   // masked rows underflow to 0
                    e[st][r] = v;
                    den += v;
                }
            den += __shfl_xor(den, 16);
            den += __shfl_xor(den, 32);
            float num = 0.f;
            #pragma unroll
            for (int st = 0; st < 3; ++st)
                #pragma unroll
                for (int r = 0; r < 4; ++r)
                    num = fmaf(e[st][r], (float)zuc[st].h[r], num);
            part = fmaf(num, __builtin_amdgcn_rcpf(den), part);
            if (jt < 3) {
                #pragma unroll
                for (int st = 0; st < 3; ++st) zuc[st] = zun[st];
            }
        }
        #pragma unroll
        for (int x = 1; x < 64; x <<= 1) part += __shfl_xor(part, x);
        if (lane == 0) out[n * 128 + d] = part;
    }
}

extern "C" void kernel_launch(void* const* d_in, const int* in_sizes, int n_in,
                              void* d_out, int out_size, void* d_ws, size_t ws_size,
                              hipStream_t stream) {
    const float* values = (const float*)d_in[0];
    const float* times  = (const float*)d_in[1];
    const int*   mask   = (const int*)d_in[2];
    const float* omega  = (const float*)d_in[3];
    const float* alpha  = (const float*)d_in[4];
    const float* W1     = (const float*)d_in[5];
    const float* b1     = (const float*)d_in[6];
    const float* W2     = (const float*)d_in[7];
    const float* b2     = (const float*)d_in[8];
    float* out = (float*)d_out;

    unsigned short* zh  = (unsigned short*)d_ws;                 // 786432 f16
    unsigned short* zhT = zh  + (size_t)786432;                  // 917504 f16
    unsigned short* w1f = zhT + (size_t)917504;                  // 520192 f16
    unsigned short* w2f = w1f + (size_t)520192;                  // 520192 f16
    unsigned long long* m64 = (unsigned long long*)(w2f + (size_t)520192);

    mask_k <<<dim3(64),  dim3(256), 0, stream>>>(mask, m64, out);
    embed_k<<<dim3(384), dim3(256), 0, stream>>>(values, times, omega, alpha, zh);
    embedT_k<<<dim3(512), dim3(256), 0, stream>>>(values, times, omega, alpha, zhT);
    wprep_k<<<dim3(127), dim3(256), 0, stream>>>(W1, w1f, 1.0f, 0);
    wprep_k<<<dim3(127), dim3(256), 0, stream>>>(W2, w2f, LOG2E, 1);
    filter_k<<<dim3(32, 16), dim3(512), 0, stream>>>(
        zh, zhT, m64, w1f, w2f, b1, b2, out);
}

// Round 17
// 75.248 us; speedup vs baseline: 1.0208x; 1.0208x over previous
//
#include <hip/hip_runtime.h>
#include <math.h>

#define NSEQ 256
#define SLEN 48
#define DIN  64
#define NCH  8
#define LOG2E 1.4426950408889634f

typedef _Float16 half8  __attribute__((ext_vector_type(8)));
typedef __fp16   fp16x2 __attribute__((ext_vector_type(2)));
typedef _Float16 h2t    __attribute__((ext_vector_type(2)));
typedef float    f32x4  __attribute__((ext_vector_type(4)));

union U8  { _Float16 h[8]; uint4 u; unsigned int w[4]; half8 v; };
union U2  { _Float16 h[4]; uint2 u; };
union UCV { fp16x2 f; h2t h; unsigned int i; };

// ---------------- K1: mask bits + out[:,127] ----------------
__global__ __launch_bounds__(256) void mask_k(const int* __restrict__ mask,
                                              unsigned long long* __restrict__ mask64,
                                              float* __restrict__ out) {
    int wid  = (blockIdx.x * 256 + threadIdx.x) >> 6;
    int lane = threadIdx.x & 63;
    if (wid >= NSEQ) return;
    int mv = (lane < SLEN) ? mask[wid * SLEN + lane] : 0;
    unsigned long long b = __ballot(mv != 0);
    if (lane == 0) { mask64[wid] = b; out[wid * 128 + 127] = b ? 1.f : 0.f; }
}

// ---------------- K2: W -> f16 fragment layout ----------------
// perm=0 (W1, A-op of L1):  row = 32kt + 8g + e
// perm=1 (W2, B-op of L2):  row = 32kt + 16(e>>2) + 4g + (e&3)   [k-axis perm π]
__global__ __launch_bounds__(256) void wprep_k(const float* __restrict__ W,
                                               unsigned short* __restrict__ Wf,
                                               float scale, int perm) {
    __shared__ float wl[DIN * DIN];
    int d = blockIdx.x;
    const float* src = W + (size_t)d * DIN * DIN;
    for (int k = threadIdx.x; k < DIN * DIN / 4; k += 256)
        ((float4*)wl)[k] = ((const float4*)src)[k];
    __syncthreads();
    for (int rr = 0; rr < 2; ++rr) {
        int idx = threadIdx.x * 2 + rr;
        int fid = idx >> 6, l = idx & 63;
        int mt = fid >> 1, kt = fid & 1, g = l >> 4, c = l & 15;
        U8 t;
        #pragma unroll
        for (int e = 0; e < 8; ++e) {
            int row = perm ? (32 * kt + 16 * (e >> 2) + 4 * g + (e & 3))
                           : (32 * kt + 8 * g + e);
            t.h[e] = (_Float16)(wl[row * DIN + (16 * mt + c)] * scale);
        }
        *(uint4*)(Wf + ((size_t)(d * 8 + fid) * 64 + l) * 8) = t.u;
    }
}

// ---------------- K3a: embedding -> f16, row-major, chunk-swizzled ----------
__global__ __launch_bounds__(256) void embed_k(const float* __restrict__ values,
                                               const float* __restrict__ times,
                                               const float* __restrict__ omega,
                                               const float* __restrict__ alpha,
                                               unsigned short* __restrict__ zh) {
    int id = blockIdx.x * 256 + threadIdx.x;
    int ch = id & 7, ns = id >> 3;
    if (ns >= NSEQ * SLEN) return;
    int s = ns % SLEN;
    float t = times[ns];
    U8 o;
    #pragma unroll
    for (int e = 0; e < 8; ++e) {
        int i = ch * 8 + e;
        float r;
        if (i == 0)       r = omega[0] * t + alpha[0];
        else if (i == 63) r = values[ns];
        else              r = __sinf(t * omega[i] + alpha[i]);
        o.h[e] = (_Float16)r;
    }
    int csw = ch ^ (s & 7);
    *(uint4*)(zh + (size_t)ns * 64 + csw * 8) = o.u;
}

// ---------------- K3b: transposed embedding zhT[n][j][s], row stride 56 -----
__global__ __launch_bounds__(256) void embedT_k(const float* __restrict__ values,
                                                const float* __restrict__ times,
                                                const float* __restrict__ omega,
                                                const float* __restrict__ alpha,
                                                unsigned short* __restrict__ zhT) {
    int id = blockIdx.x * 256 + threadIdx.x;
    int unit = id & 511, n = id >> 9;
    int sc = unit >> 6;
    if (sc >= 6) return;
    int j = unit & 63;
    int s0 = sc * 8;
    const float* tp = times + n * SLEN + s0;
    float4 t0 = *(const float4*)tp, t1 = *(const float4*)(tp + 4);
    float tv[8] = {t0.x, t0.y, t0.z, t0.w, t1.x, t1.y, t1.z, t1.w};
    U8 o;
    if (j == 0) {
        float om = omega[0], al = alpha[0];
        #pragma unroll
        for (int e = 0; e < 8; ++e) o.h[e] = (_Float16)(om * tv[e] + al);
    } else if (j == 63) {
        const float* vp = values + n * SLEN + s0;
        float4 v0 = *(const float4*)vp, v1 = *(const float4*)(vp + 4);
        float vv[8] = {v0.x, v0.y, v0.z, v0.w, v1.x, v1.y, v1.z, v1.w};
        #pragma unroll
        for (int e = 0; e < 8; ++e) o.h[e] = (_Float16)vv[e];
    } else {
        float om = omega[j], al = alpha[j];
        #pragma unroll
        for (int e = 0; e < 8; ++e) o.h[e] = (_Float16)__sinf(tv[e] * om + al);
    }
    *(uint4*)(zhT + (size_t)n * 3584 + j * 56 + s0) = o.u;
}

// ---------------- K4: main fused kernel — VALU-trimmed body ----------------
// Structure = r16 (512-thread blocks, launch_bounds(512,2) no-spill point,
// zero LDS/barriers, XCD remap, rotated zf prefetch). NEW: three VALU cuts
// (~35% of per-unit ops):
//  (1) b1 fed as the MFMA C-operand (kills 48 accumulator-init movs/unit)
//  (2) pack-then-relu: cvt_pkrtz then packed v_pk_max (48 fmax+24 cvt -> 36)
//  (3) fdot2 epilogue: v_dot2_f32_f16 for num AND den (kills 48 cvt + 48 fma
//      + 24 adds; e carried as f16 pairs, error ~1e-3 << 0.075 threshold)
__global__ __launch_bounds__(512, 2) void filter_k(
    const unsigned short* __restrict__ zh,
    const unsigned short* __restrict__ zhT,
    const unsigned long long* __restrict__ mask64,
    const unsigned short* __restrict__ w1f, const unsigned short* __restrict__ w2f,
    const float* __restrict__ b1, const float* __restrict__ b2,
    float* __restrict__ out)
{
    const int tid = threadIdx.x;
    const int w = tid >> 6, lane = tid & 63;
    const int g = lane >> 4, c = lane & 15;

    // XCD-aware remap: 512 blocks; xcd = lin%8, slot = lin/8 (0..63)
    const int lin   = blockIdx.y * 32 + blockIdx.x;
    const int xcd   = lin & 7, slot = lin >> 3;
    const int octet = xcd * 2 + (slot & 1);     // 0..15 (2 octets per XCD)
    const int nchk  = slot >> 1;                // 0..31
    const int d = octet * 8 + w;
    if (d >= 127) return;                       // whole-wave exit; no barriers
    const int nb = nchk * NCH;

    // per-d constants (L2-resident, reused across 8 n's)
    half8 w1fr[8], w2fr[8];
    #pragma unroll
    for (int f = 0; f < 8; ++f) {
        w1fr[f] = *(const half8*)(w1f + ((size_t)(d * 8 + f) * 64 + lane) * 8);
        w2fr[f] = *(const half8*)(w2f + ((size_t)(d * 8 + f) * 64 + lane) * 8);
    }
    f32x4 b1q[4];
    #pragma unroll
    for (int hm = 0; hm < 4; ++hm)
        b1q[hm] = *(const f32x4*)(b1 + d * DIN + 16 * hm + 4 * g);
    float b2v[4];
    #pragma unroll
    for (int jt = 0; jt < 4; ++jt)
        b2v[jt] = b2[d * DIN + 16 * jt + c] * LOG2E;

    // hoisted global-address offsets (element units)
    int zoff[2][3];   // b128 frag reads: row s=16st+c, chunk (4kt+g)^(s&7)
    #pragma unroll
    for (int kt = 0; kt < 2; ++kt)
        #pragma unroll
        for (int st = 0; st < 3; ++st) {
            int s = 16 * st + c;
            zoff[kt][st] = s * 64 + (((4 * kt + g) ^ (s & 7)) << 3);
        }
    const int ztbase = c * 56 + 4 * g;   // zT: row j=16jt+c, s=16st+4g

    UCV one2;
    one2.f = (fp16x2){(__fp16)1.f, (__fp16)1.f};
    const fp16x2 zero2 = {(__fp16)0.f, (__fp16)0.f};

    // ---- preload unit 0's zf + mask (rotation seed)
    half8 zf[2][3];
    unsigned long long mw;
    {
        const unsigned short* zl = zh + (size_t)nb * 3072;
        #pragma unroll
        for (int kt = 0; kt < 2; ++kt)
            #pragma unroll
            for (int st = 0; st < 3; ++st)
                zf[kt][st] = *(const half8*)(zl + zoff[kt][st]);
        mw = mask64[nb];
    }

    #pragma unroll 1
    for (int ni = 0; ni < NCH; ++ni) {
        const int n = nb + ni;
        const unsigned short* zt = zhT + (size_t)n * 3584;

        // mask -> additive bias per (st,r): s = 16st+4g+r; 0 or -16384
        f32x4 binit[3];
        #pragma unroll
        for (int st = 0; st < 3; ++st)
            #pragma unroll
            for (int r = 0; r < 4; ++r)
                binit[st][r] = ((mw >> (16 * st + 4 * g + r)) & 1ull) ? 0.f : -16384.f;

        // ---- layer 1: H^T = W1^T x Z^T (b1 enters as kt=0's C-operand)
        f32x4 aH[4][3];
        #pragma unroll
        for (int hm = 0; hm < 4; ++hm)
            #pragma unroll
            for (int st = 0; st < 3; ++st) {
                aH[hm][st] = __builtin_amdgcn_mfma_f32_16x16x32_f16(
                    w1fr[hm * 2 + 0], zf[0][st], b1q[hm], 0, 0, 0);
                aH[hm][st] = __builtin_amdgcn_mfma_f32_16x16x32_f16(
                    w1fr[hm * 2 + 1], zf[1][st], aH[hm][st], 0, 0, 0);
            }

        // ---- rotation: zf consumed -> issue next unit's zf + mask now
        if (ni + 1 < NCH) {
            const unsigned short* zl = zh + (size_t)(n + 1) * 3072;
            #pragma unroll
            for (int kt = 0; kt < 2; ++kt)
                #pragma unroll
                for (int st = 0; st < 3; ++st)
                    zf[kt][st] = *(const half8*)(zl + zoff[kt][st]);
            mw = mask64[n + 1];
        }

        // pack-then-relu: cvt_pkrtz -> packed max with 0 (registers only)
        unsigned int pk[4][3][2];
        #pragma unroll
        for (int hm = 0; hm < 4; ++hm)
            #pragma unroll
            for (int st = 0; st < 3; ++st) {
                UCV a, b;
                a.f = __builtin_elementwise_max(
                    __builtin_amdgcn_cvt_pkrtz(aH[hm][st][0], aH[hm][st][1]), zero2);
                b.f = __builtin_elementwise_max(
                    __builtin_amdgcn_cvt_pkrtz(aH[hm][st][2], aH[hm][st][3]), zero2);
                pk[hm][st][0] = a.i;
                pk[hm][st][1] = b.i;
            }

        // ---- per-jt: L2 MFMA (k-permuted, A lane-local) + fdot2 softmax
        U2 zuc[3], zun[3];
        #pragma unroll
        for (int st = 0; st < 3; ++st)
            zuc[st].u = *(const uint2*)(zt + ztbase + st * 16);
        float part = 0.f;
        #pragma unroll
        for (int jt = 0; jt < 4; ++jt) {
            f32x4 aL3[3];
            #pragma unroll
            for (int st = 0; st < 3; ++st) {
                aL3[st] = binit[st] + b2v[jt];     // bias + mask fold at C-init
                #pragma unroll
                for (int kt = 0; kt < 2; ++kt) {
                    U8 hfu;
                    hfu.w[0] = pk[2 * kt + 0][st][0];
                    hfu.w[1] = pk[2 * kt + 0][st][1];
                    hfu.w[2] = pk[2 * kt + 1][st][0];
                    hfu.w[3] = pk[2 * kt + 1][st][1];
                    aL3[st] = __builtin_amdgcn_mfma_f32_16x16x32_f16(
                        hfu.v, w2fr[jt * 2 + kt], aL3[st], 0, 0, 0);
                }
            }
            if (jt < 3) {
                #pragma unroll
                for (int st = 0; st < 3; ++st)
                    zun[st].u = *(const uint2*)(zt + ztbase + (jt + 1) * 896 + st * 16);
            }
            float num = 0.f, den = 0.f;
            #pragma unroll
            for (int st = 0; st < 3; ++st) {
                float v0 = exp2f(aL3[st][0]), v1 = exp2f(aL3[st][1]);
                float v2 = exp2f(aL3[st][2]), v3 = exp2f(aL3[st][3]);
                UCV p01, p23, z01, z23;
                p01.f = __builtin_amdgcn_cvt_pkrtz(v0, v1);
                p23.f = __builtin_amdgcn_cvt_pkrtz(v2, v3);
                z01.i = zuc[st].u.x;
                z23.i = zuc[st].u.y;
                num = __builtin_amdgcn_fdot2(p01.h, z01.h, num, false);
                num = __builtin_amdgcn_fdot2(p23.h, z23.h, num, false);
                den = __builtin_amdgcn_fdot2(p01.h, one2.h, den, false);
                den = __builtin_amdgcn_fdot2(p23.h, one2.h, den, false);
            }
            den += __shfl_xor(den, 16);
            den += __shfl_xor(den, 32);
            part = fmaf(num, __builtin_amdgcn_rcpf(den), part);
            if (jt < 3) {
                #pragma unroll
                for (int st = 0; st < 3; ++st) zuc[st] = zun[st];
            }
        }
        #pragma unroll
        for (int x = 1; x < 64; x <<= 1) part += __shfl_xor(part, x);
        if (lane == 0) out[n * 128 + d] = part;
    }
}

extern "C" void kernel_launch(void* const* d_in, const int* in_sizes, int n_in,
                              void* d_out, int out_size, void* d_ws, size_t ws_size,
                              hipStream_t stream) {
    const float* values = (const float*)d_in[0];
    const float* times  = (const float*)d_in[1];
    const int*   mask   = (const int*)d_in[2];
    const float* omega  = (const float*)d_in[3];
    const float* alpha  = (const float*)d_in[4];
    const float* W1     = (const float*)d_in[5];
    const float* b1     = (const float*)d_in[6];
    const float* W2     = (const float*)d_in[7];
    const float* b2     = (const float*)d_in[8];
    float* out = (float*)d_out;

    unsigned short* zh  = (unsigned short*)d_ws;                 // 786432 f16
    unsigned short* zhT = zh  + (size_t)786432;                  // 917504 f16
    unsigned short* w1f = zhT + (size_t)917504;                  // 520192 f16
    unsigned short* w2f = w1f + (size_t)520192;                  // 520192 f16
    unsigned long long* m64 = (unsigned long long*)(w2f + (size_t)520192);

    mask_k <<<dim3(64),  dim3(256), 0, stream>>>(mask, m64, out);
    embed_k<<<dim3(384), dim3(256), 0, stream>>>(values, times, omega, alpha, zh);
    embedT_k<<<dim3(512), dim3(256), 0, stream>>>(values, times, omega, alpha, zhT);
    wprep_k<<<dim3(127), dim3(256), 0, stream>>>(W1, w1f, 1.0f, 0);
    wprep_k<<<dim3(127), dim3(256), 0, stream>>>(W2, w2f, LOG2E, 1);
    filter_k<<<dim3(32, 16), dim3(512), 0, stream>>>(
        zh, zhT, m64, w1f, w2f, b1, b2, out);
}

// Round 18
// 71.111 us; speedup vs baseline: 1.0802x; 1.0582x over previous
//
#include <hip/hip_runtime.h>
#include <math.h>

#define NSEQ 256
#define SLEN 48
#define DIN  64
#define NCH  8
#define LOG2E 1.4426950408889634f

typedef _Float16 half8  __attribute__((ext_vector_type(8)));
typedef __fp16   fp16x2 __attribute__((ext_vector_type(2)));
typedef _Float16 h2t    __attribute__((ext_vector_type(2)));
typedef float    f32x4  __attribute__((ext_vector_type(4)));

union U8  { _Float16 h[8]; uint4 u; unsigned int w[4]; half8 v; };
union U2  { _Float16 h[4]; uint2 u; };
union UCV { fp16x2 f; h2t h; unsigned int i; };

// ---------------- K1: mask bits + out[:,127] ----------------
__global__ __launch_bounds__(256) void mask_k(const int* __restrict__ mask,
                                              unsigned long long* __restrict__ mask64,
                                              float* __restrict__ out) {
    int wid  = (blockIdx.x * 256 + threadIdx.x) >> 6;
    int lane = threadIdx.x & 63;
    if (wid >= NSEQ) return;
    int mv = (lane < SLEN) ? mask[wid * SLEN + lane] : 0;
    unsigned long long b = __ballot(mv != 0);
    if (lane == 0) { mask64[wid] = b; out[wid * 128 + 127] = b ? 1.f : 0.f; }
}

// ---------------- K2: W -> f16 fragment layout ----------------
// perm=0 (W1, A-op of L1):  row = 32kt + 8g + e
// perm=1 (W2, B-op of L2):  row = 32kt + 16(e>>2) + 4g + (e&3)   [k-axis perm π]
__global__ __launch_bounds__(256) void wprep_k(const float* __restrict__ W,
                                               unsigned short* __restrict__ Wf,
                                               float scale, int perm) {
    __shared__ float wl[DIN * DIN];
    int d = blockIdx.x;
    const float* src = W + (size_t)d * DIN * DIN;
    for (int k = threadIdx.x; k < DIN * DIN / 4; k += 256)
        ((float4*)wl)[k] = ((const float4*)src)[k];
    __syncthreads();
    for (int rr = 0; rr < 2; ++rr) {
        int idx = threadIdx.x * 2 + rr;
        int fid = idx >> 6, l = idx & 63;
        int mt = fid >> 1, kt = fid & 1, g = l >> 4, c = l & 15;
        U8 t;
        #pragma unroll
        for (int e = 0; e < 8; ++e) {
            int row = perm ? (32 * kt + 16 * (e >> 2) + 4 * g + (e & 3))
                           : (32 * kt + 8 * g + e);
            t.h[e] = (_Float16)(wl[row * DIN + (16 * mt + c)] * scale);
        }
        *(uint4*)(Wf + ((size_t)(d * 8 + fid) * 64 + l) * 8) = t.u;
    }
}

// ---------------- K3a: embedding -> f16, row-major, chunk-swizzled ----------
__global__ __launch_bounds__(256) void embed_k(const float* __restrict__ values,
                                               const float* __restrict__ times,
                                               const float* __restrict__ omega,
                                               const float* __restrict__ alpha,
                                               unsigned short* __restrict__ zh) {
    int id = blockIdx.x * 256 + threadIdx.x;
    int ch = id & 7, ns = id >> 3;
    if (ns >= NSEQ * SLEN) return;
    int s = ns % SLEN;
    float t = times[ns];
    U8 o;
    #pragma unroll
    for (int e = 0; e < 8; ++e) {
        int i = ch * 8 + e;
        float r;
        if (i == 0)       r = omega[0] * t + alpha[0];
        else if (i == 63) r = values[ns];
        else              r = __sinf(t * omega[i] + alpha[i]);
        o.h[e] = (_Float16)r;
    }
    int csw = ch ^ (s & 7);
    *(uint4*)(zh + (size_t)ns * 64 + csw * 8) = o.u;
}

// ---------------- K3b: transposed embedding zhT[n][j][s], row stride 56 -----
__global__ __launch_bounds__(256) void embedT_k(const float* __restrict__ values,
                                                const float* __restrict__ times,
                                                const float* __restrict__ omega,
                                                const float* __restrict__ alpha,
                                                unsigned short* __restrict__ zhT) {
    int id = blockIdx.x * 256 + threadIdx.x;
    int unit = id & 511, n = id >> 9;
    int sc = unit >> 6;
    if (sc >= 6) return;
    int j = unit & 63;
    int s0 = sc * 8;
    const float* tp = times + n * SLEN + s0;
    float4 t0 = *(const float4*)tp, t1 = *(const float4*)(tp + 4);
    float tv[8] = {t0.x, t0.y, t0.z, t0.w, t1.x, t1.y, t1.z, t1.w};
    U8 o;
    if (j == 0) {
        float om = omega[0], al = alpha[0];
        #pragma unroll
        for (int e = 0; e < 8; ++e) o.h[e] = (_Float16)(om * tv[e] + al);
    } else if (j == 63) {
        const float* vp = values + n * SLEN + s0;
        float4 v0 = *(const float4*)vp, v1 = *(const float4*)(vp + 4);
        float vv[8] = {v0.x, v0.y, v0.z, v0.w, v1.x, v1.y, v1.z, v1.w};
        #pragma unroll
        for (int e = 0; e < 8; ++e) o.h[e] = (_Float16)vv[e];
    } else {
        float om = omega[j], al = alpha[j];
        #pragma unroll
        for (int e = 0; e < 8; ++e) o.h[e] = (_Float16)__sinf(tv[e] * om + al);
    }
    *(uint4*)(zhT + (size_t)n * 3584 + j * 56 + s0) = o.u;
}

// ---------------- K4: main fused kernel — shfl-free den via ones-MFMA -------
// Structure = r17 (512-thread blocks, launch_bounds(512,2) no-spill, zero
// LDS/barriers, XCD remap, rotated zf prefetch, b1-as-C, pack-relu, fdot2).
// NEW:
//  (1) den_j = sum_s e[s][j] computed by MFMA with A=ones: B-fragment = each
//      lane's OWN packed e-words (any k-order valid since A=ones) -> the 2
//      serial den shuffles per jt (8/unit, ~960 cyc) become 2 MFMAs, and den
//      lands per-lane in the D register. Masked e are exactly 0 (underflow).
//  (2) b2 DELETED: softmax is over s; b2[d,j] is constant along s and cancels
//      exactly. binit (mask bias) feeds the L2 MFMA C-operand directly.
__global__ __launch_bounds__(512, 2) void filter_k(
    const unsigned short* __restrict__ zh,
    const unsigned short* __restrict__ zhT,
    const unsigned long long* __restrict__ mask64,
    const unsigned short* __restrict__ w1f, const unsigned short* __restrict__ w2f,
    const float* __restrict__ b1,
    float* __restrict__ out)
{
    const int tid = threadIdx.x;
    const int w = tid >> 6, lane = tid & 63;
    const int g = lane >> 4, c = lane & 15;

    // XCD-aware remap: 512 blocks; xcd = lin%8, slot = lin/8 (0..63)
    const int lin   = blockIdx.y * 32 + blockIdx.x;
    const int xcd   = lin & 7, slot = lin >> 3;
    const int octet = xcd * 2 + (slot & 1);     // 0..15 (2 octets per XCD)
    const int nchk  = slot >> 1;                // 0..31
    const int d = octet * 8 + w;
    if (d >= 127) return;                       // whole-wave exit; no barriers
    const int nb = nchk * NCH;

    // per-d constants (L2-resident, reused across 8 n's)
    half8 w1fr[8], w2fr[8];
    #pragma unroll
    for (int f = 0; f < 8; ++f) {
        w1fr[f] = *(const half8*)(w1f + ((size_t)(d * 8 + f) * 64 + lane) * 8);
        w2fr[f] = *(const half8*)(w2f + ((size_t)(d * 8 + f) * 64 + lane) * 8);
    }
    f32x4 b1q[4];
    #pragma unroll
    for (int hm = 0; hm < 4; ++hm)
        b1q[hm] = *(const f32x4*)(b1 + d * DIN + 16 * hm + 4 * g);

    // hoisted global-address offsets (element units)
    int zoff[2][3];   // b128 frag reads: row s=16st+c, chunk (4kt+g)^(s&7)
    #pragma unroll
    for (int kt = 0; kt < 2; ++kt)
        #pragma unroll
        for (int st = 0; st < 3; ++st) {
            int s = 16 * st + c;
            zoff[kt][st] = s * 64 + (((4 * kt + g) ^ (s & 7)) << 3);
        }
    const int ztbase = c * 56 + 4 * g;   // zT: row j=16jt+c, s=16st+4g

    const fp16x2 zero2 = {(__fp16)0.f, (__fp16)0.f};
    U8 ones;
    #pragma unroll
    for (int e = 0; e < 8; ++e) ones.h[e] = (_Float16)1.f;
    const f32x4 zero4 = {0.f, 0.f, 0.f, 0.f};

    // ---- preload unit 0's zf + mask (rotation seed)
    half8 zf[2][3];
    unsigned long long mw;
    {
        const unsigned short* zl = zh + (size_t)nb * 3072;
        #pragma unroll
        for (int kt = 0; kt < 2; ++kt)
            #pragma unroll
            for (int st = 0; st < 3; ++st)
                zf[kt][st] = *(const half8*)(zl + zoff[kt][st]);
        mw = mask64[nb];
    }

    #pragma unroll 1
    for (int ni = 0; ni < NCH; ++ni) {
        const int n = nb + ni;
        const unsigned short* zt = zhT + (size_t)n * 3584;

        // mask -> additive bias per (st,r): s = 16st+4g+r; 0 or -16384
        f32x4 binit[3];
        #pragma unroll
        for (int st = 0; st < 3; ++st)
            #pragma unroll
            for (int r = 0; r < 4; ++r)
                binit[st][r] = ((mw >> (16 * st + 4 * g + r)) & 1ull) ? 0.f : -16384.f;

        // ---- layer 1: H^T = W1^T x Z^T (b1 enters as kt=0's C-operand)
        f32x4 aH[4][3];
        #pragma unroll
        for (int hm = 0; hm < 4; ++hm)
            #pragma unroll
            for (int st = 0; st < 3; ++st) {
                aH[hm][st] = __builtin_amdgcn_mfma_f32_16x16x32_f16(
                    w1fr[hm * 2 + 0], zf[0][st], b1q[hm], 0, 0, 0);
                aH[hm][st] = __builtin_amdgcn_mfma_f32_16x16x32_f16(
                    w1fr[hm * 2 + 1], zf[1][st], aH[hm][st], 0, 0, 0);
            }

        // ---- rotation: zf consumed -> issue next unit's zf + mask now
        if (ni + 1 < NCH) {
            const unsigned short* zl = zh + (size_t)(n + 1) * 3072;
            #pragma unroll
            for (int kt = 0; kt < 2; ++kt)
                #pragma unroll
                for (int st = 0; st < 3; ++st)
                    zf[kt][st] = *(const half8*)(zl + zoff[kt][st]);
            mw = mask64[n + 1];
        }

        // pack-then-relu: cvt_pkrtz -> packed max with 0 (registers only)
        unsigned int pk[4][3][2];
        #pragma unroll
        for (int hm = 0; hm < 4; ++hm)
            #pragma unroll
            for (int st = 0; st < 3; ++st) {
                UCV a, b;
                a.f = __builtin_elementwise_max(
                    __builtin_amdgcn_cvt_pkrtz(aH[hm][st][0], aH[hm][st][1]), zero2);
                b.f = __builtin_elementwise_max(
                    __builtin_amdgcn_cvt_pkrtz(aH[hm][st][2], aH[hm][st][3]), zero2);
                pk[hm][st][0] = a.i;
                pk[hm][st][1] = b.i;
            }

        // ---- per-jt: L2 MFMA (k-permuted, A lane-local; binit as C) +
        //      exp/pack + ones-MFMA den (no cross-lane) + fdot2 num
        U2 zuc[3], zun[3];
        #pragma unroll
        for (int st = 0; st < 3; ++st)
            zuc[st].u = *(const uint2*)(zt + ztbase + st * 16);
        float part = 0.f;
        #pragma unroll
        for (int jt = 0; jt < 4; ++jt) {
            f32x4 aL3[3];
            #pragma unroll
            for (int st = 0; st < 3; ++st) {
                U8 hfu;
                hfu.w[0] = pk[0][st][0];
                hfu.w[1] = pk[0][st][1];
                hfu.w[2] = pk[1][st][0];
                hfu.w[3] = pk[1][st][1];
                aL3[st] = __builtin_amdgcn_mfma_f32_16x16x32_f16(
                    hfu.v, w2fr[jt * 2 + 0], binit[st], 0, 0, 0);
                hfu.w[0] = pk[2][st][0];
                hfu.w[1] = pk[2][st][1];
                hfu.w[2] = pk[3][st][0];
                hfu.w[3] = pk[3][st][1];
                aL3[st] = __builtin_amdgcn_mfma_f32_16x16x32_f16(
                    hfu.v, w2fr[jt * 2 + 1], aL3[st], 0, 0, 0);
            }
            if (jt < 3) {
                #pragma unroll
                for (int st = 0; st < 3; ++st)
                    zun[st].u = *(const uint2*)(zt + ztbase + (jt + 1) * 896 + st * 16);
            }
            // exp -> packed f16 e-words
            UCV p01[3], p23[3];
            #pragma unroll
            for (int st = 0; st < 3; ++st) {
                float v0 = exp2f(aL3[st][0]), v1 = exp2f(aL3[st][1]);
                float v2 = exp2f(aL3[st][2]), v3 = exp2f(aL3[st][3]);
                p01[st].f = __builtin_amdgcn_cvt_pkrtz(v0, v1);
                p23[st].f = __builtin_amdgcn_cvt_pkrtz(v2, v3);
            }
            // den via ones-MFMA: B-frag = own e-words (k-order irrelevant)
            U8 ef0, ef1;
            ef0.w[0] = p01[0].i; ef0.w[1] = p23[0].i;
            ef0.w[2] = p01[1].i; ef0.w[3] = p23[1].i;
            ef1.w[0] = p01[2].i; ef1.w[1] = p23[2].i;
            ef1.w[2] = 0u;       ef1.w[3] = 0u;
            f32x4 dv = __builtin_amdgcn_mfma_f32_16x16x32_f16(
                ones.v, ef0.v, zero4, 0, 0, 0);
            dv = __builtin_amdgcn_mfma_f32_16x16x32_f16(
                ones.v, ef1.v, dv, 0, 0, 0);
            // num via fdot2 against zT
            float num = 0.f;
            #pragma unroll
            for (int st = 0; st < 3; ++st) {
                UCV z01, z23;
                z01.i = zuc[st].u.x;
                z23.i = zuc[st].u.y;
                num = __builtin_amdgcn_fdot2(p01[st].h, z01.h, num, false);
                num = __builtin_amdgcn_fdot2(p23[st].h, z23.h, num, false);
            }
            part = fmaf(num, __builtin_amdgcn_rcpf(dv[0]), part);
            if (jt < 3) {
                #pragma unroll
                for (int st = 0; st < 3; ++st) zuc[st] = zun[st];
            }
        }
        #pragma unroll
        for (int x = 1; x < 64; x <<= 1) part += __shfl_xor(part, x);
        if (lane == 0) out[n * 128 + d] = part;
    }
}

extern "C" void kernel_launch(void* const* d_in, const int* in_sizes, int n_in,
                              void* d_out, int out_size, void* d_ws, size_t ws_size,
                              hipStream_t stream) {
    const float* values = (const float*)d_in[0];
    const float* times  = (const float*)d_in[1];
    const int*   mask   = (const int*)d_in[2];
    const float* omega  = (const float*)d_in[3];
    const float* alpha  = (const float*)d_in[4];
    const float* W1     = (const float*)d_in[5];
    const float* b1     = (const float*)d_in[6];
    const float* W2     = (const float*)d_in[7];
    // b2 (d_in[8]) is mathematically irrelevant: constant along the softmax
    // axis (s), so it cancels in softmax. Not read.
    float* out = (float*)d_out;

    unsigned short* zh  = (unsigned short*)d_ws;                 // 786432 f16
    unsigned short* zhT = zh  + (size_t)786432;                  // 917504 f16
    unsigned short* w1f = zhT + (size_t)917504;                  // 520192 f16
    unsigned short* w2f = w1f + (size_t)520192;                  // 520192 f16
    unsigned long long* m64 = (unsigned long long*)(w2f + (size_t)520192);

    mask_k <<<dim3(64),  dim3(256), 0, stream>>>(mask, m64, out);
    embed_k<<<dim3(384), dim3(256), 0, stream>>>(values, times, omega, alpha, zh);
    embedT_k<<<dim3(512), dim3(256), 0, stream>>>(values, times, omega, alpha, zhT);
    wprep_k<<<dim3(127), dim3(256), 0, stream>>>(W1, w1f, 1.0f, 0);
    wprep_k<<<dim3(127), dim3(256), 0, stream>>>(W2, w2f, LOG2E, 1);
    filter_k<<<dim3(32, 16), dim3(512), 0, stream>>>(
        zh, zhT, m64, w1f, w2f, b1, out);
}

// Round 19
// 58.659 us; speedup vs baseline: 1.3095x; 1.2123x over previous
//
#include <hip/hip_runtime.h>
#include <math.h>

#define NSEQ 256
#define SLEN 48
#define DIN  64
#define NCH  8
#define LOG2E 1.4426950408889634f

typedef _Float16 half8  __attribute__((ext_vector_type(8)));
typedef __fp16   fp16x2 __attribute__((ext_vector_type(2)));
typedef _Float16 h2t    __attribute__((ext_vector_type(2)));
typedef float    f32x4  __attribute__((ext_vector_type(4)));

union U8  { _Float16 h[8]; uint4 u; unsigned int w[4]; half8 v; };
union U2  { _Float16 h[4]; uint2 u; };
union UCV { fp16x2 f; h2t h; unsigned int i; };
union UFI { float f; int i; };

// DPP 64-lane sum: 6 VALU adds, no DS pipe. Result valid in lane 63.
__device__ __forceinline__ float wave_sum_dpp(float x) {
    UFI v, t;
    v.f = x;
    t.i = __builtin_amdgcn_update_dpp(0, v.i, 0xB1,  0xF, 0xF, true);  // quad_perm [1,0,3,2]
    v.f += t.f;
    t.i = __builtin_amdgcn_update_dpp(0, v.i, 0x4E,  0xF, 0xF, true);  // quad_perm [2,3,0,1]
    v.f += t.f;
    t.i = __builtin_amdgcn_update_dpp(0, v.i, 0x141, 0xF, 0xF, true);  // row_half_mirror
    v.f += t.f;
    t.i = __builtin_amdgcn_update_dpp(0, v.i, 0x140, 0xF, 0xF, true);  // row_mirror
    v.f += t.f;
    t.i = __builtin_amdgcn_update_dpp(0, v.i, 0x142, 0xA, 0xF, false); // row_bcast:15 -> rows 1,3
    v.f += t.f;
    t.i = __builtin_amdgcn_update_dpp(0, v.i, 0x143, 0xC, 0xF, false); // row_bcast:31 -> rows 2,3
    v.f += t.f;
    return v.f;
}

// ---------------- K1: ALL prep fused into one launch ----------------
// blocks 0..126: W1 frag prep | 127..253: W2 frag prep (k-perm pi, *log2e)
// blocks 254..637: embed (zh) | 638..1149: embedT (zhT) | 1150..1213: mask
__global__ __launch_bounds__(256) void prep_k(
    const float* __restrict__ values, const float* __restrict__ times,
    const int* __restrict__ mask,
    const float* __restrict__ omega, const float* __restrict__ alpha,
    const float* __restrict__ W1, const float* __restrict__ W2,
    unsigned short* __restrict__ zh, unsigned short* __restrict__ zhT,
    unsigned short* __restrict__ w1f, unsigned short* __restrict__ w2f,
    unsigned long long* __restrict__ mask64, float* __restrict__ out)
{
    const int bid = blockIdx.x;
    if (bid < 254) {
        // ---- weight fragment prep
        const int isW2 = (bid >= 127);
        const float* W = isW2 ? W2 : W1;
        unsigned short* Wf = isW2 ? w2f : w1f;
        const float scale = isW2 ? LOG2E : 1.0f;
        const int d = isW2 ? bid - 127 : bid;
        __shared__ float wl[DIN * DIN];
        const float* src = W + (size_t)d * DIN * DIN;
        for (int k = threadIdx.x; k < DIN * DIN / 4; k += 256)
            ((float4*)wl)[k] = ((const float4*)src)[k];
        __syncthreads();
        for (int rr = 0; rr < 2; ++rr) {
            int idx = threadIdx.x * 2 + rr;
            int fid = idx >> 6, l = idx & 63;
            int mt = fid >> 1, kt = fid & 1, g = l >> 4, c = l & 15;
            U8 t;
            #pragma unroll
            for (int e = 0; e < 8; ++e) {
                int row = isW2 ? (32 * kt + 16 * (e >> 2) + 4 * g + (e & 3))
                               : (32 * kt + 8 * g + e);
                t.h[e] = (_Float16)(wl[row * DIN + (16 * mt + c)] * scale);
            }
            *(uint4*)(Wf + ((size_t)(d * 8 + fid) * 64 + l) * 8) = t.u;
        }
    } else if (bid < 638) {
        // ---- embed: zh[n*s][64], chunk-swizzled
        int id = (bid - 254) * 256 + threadIdx.x;
        int ch = id & 7, ns = id >> 3;
        if (ns >= NSEQ * SLEN) return;
        int s = ns % SLEN;
        float t = times[ns];
        U8 o;
        #pragma unroll
        for (int e = 0; e < 8; ++e) {
            int i = ch * 8 + e;
            float r;
            if (i == 0)       r = omega[0] * t + alpha[0];
            else if (i == 63) r = values[ns];
            else              r = __sinf(t * omega[i] + alpha[i]);
            o.h[e] = (_Float16)r;
        }
        int csw = ch ^ (s & 7);
        *(uint4*)(zh + (size_t)ns * 64 + csw * 8) = o.u;
    } else if (bid < 1150) {
        // ---- embedT: zhT[n][j][s], row stride 56
        int id = (bid - 638) * 256 + threadIdx.x;
        int unit = id & 511, n = id >> 9;
        int sc = unit >> 6;
        if (sc >= 6) return;
        int j = unit & 63;
        int s0 = sc * 8;
        const float* tp = times + n * SLEN + s0;
        float4 t0 = *(const float4*)tp, t1 = *(const float4*)(tp + 4);
        float tv[8] = {t0.x, t0.y, t0.z, t0.w, t1.x, t1.y, t1.z, t1.w};
        U8 o;
        if (j == 0) {
            float om = omega[0], al = alpha[0];
            #pragma unroll
            for (int e = 0; e < 8; ++e) o.h[e] = (_Float16)(om * tv[e] + al);
        } else if (j == 63) {
            const float* vp = values + n * SLEN + s0;
            float4 v0 = *(const float4*)vp, v1 = *(const float4*)(vp + 4);
            float vv[8] = {v0.x, v0.y, v0.z, v0.w, v1.x, v1.y, v1.z, v1.w};
            #pragma unroll
            for (int e = 0; e < 8; ++e) o.h[e] = (_Float16)vv[e];
        } else {
            float om = omega[j], al = alpha[j];
            #pragma unroll
            for (int e = 0; e < 8; ++e) o.h[e] = (_Float16)__sinf(tv[e] * om + al);
        }
        *(uint4*)(zhT + (size_t)n * 3584 + j * 56 + s0) = o.u;
    } else {
        // ---- mask bits + out[:,127]
        int wid  = ((bid - 1150) * 256 + threadIdx.x) >> 6;
        int lane = threadIdx.x & 63;
        if (wid >= NSEQ) return;
        int mv = (lane < SLEN) ? mask[wid * SLEN + lane] : 0;
        unsigned long long b = __ballot(mv != 0);
        if (lane == 0) { mask64[wid] = b; out[wid * 128 + 127] = b ? 1.f : 0.f; }
    }
}

// ---------------- K4: main fused kernel ----------------
// = r18 (512-thread blocks, launch_bounds(512,2) no-spill, zero LDS/barriers,
// XCD remap, rotated zf prefetch, b1-as-C, pack-relu, ones-MFMA den, fdot2
// num, b2 algebraically deleted) + NEW: DPP final reduce (6 VALU adds
// replace 6 serial DS shuffles; result in lane 63).
__global__ __launch_bounds__(512, 2) void filter_k(
    const unsigned short* __restrict__ zh,
    const unsigned short* __restrict__ zhT,
    const unsigned long long* __restrict__ mask64,
    const unsigned short* __restrict__ w1f, const unsigned short* __restrict__ w2f,
    const float* __restrict__ b1,
    float* __restrict__ out)
{
    const int tid = threadIdx.x;
    const int w = tid >> 6, lane = tid & 63;
    const int g = lane >> 4, c = lane & 15;

    // XCD-aware remap: 512 blocks; xcd = lin%8, slot = lin/8 (0..63)
    const int lin   = blockIdx.y * 32 + blockIdx.x;
    const int xcd   = lin & 7, slot = lin >> 3;
    const int octet = xcd * 2 + (slot & 1);     // 0..15 (2 octets per XCD)
    const int nchk  = slot >> 1;                // 0..31
    const int d = octet * 8 + w;
    if (d >= 127) return;                       // whole-wave exit; no barriers
    const int nb = nchk * NCH;

    // per-d constants (L2-resident, reused across 8 n's)
    half8 w1fr[8], w2fr[8];
    #pragma unroll
    for (int f = 0; f < 8; ++f) {
        w1fr[f] = *(const half8*)(w1f + ((size_t)(d * 8 + f) * 64 + lane) * 8);
        w2fr[f] = *(const half8*)(w2f + ((size_t)(d * 8 + f) * 64 + lane) * 8);
    }
    f32x4 b1q[4];
    #pragma unroll
    for (int hm = 0; hm < 4; ++hm)
        b1q[hm] = *(const f32x4*)(b1 + d * DIN + 16 * hm + 4 * g);

    // hoisted global-address offsets (element units)
    int zoff[2][3];   // b128 frag reads: row s=16st+c, chunk (4kt+g)^(s&7)
    #pragma unroll
    for (int kt = 0; kt < 2; ++kt)
        #pragma unroll
        for (int st = 0; st < 3; ++st) {
            int s = 16 * st + c;
            zoff[kt][st] = s * 64 + (((4 * kt + g) ^ (s & 7)) << 3);
        }
    const int ztbase = c * 56 + 4 * g;   // zT: row j=16jt+c, s=16st+4g

    const fp16x2 zero2 = {(__fp16)0.f, (__fp16)0.f};
    U8 ones;
    #pragma unroll
    for (int e = 0; e < 8; ++e) ones.h[e] = (_Float16)1.f;
    const f32x4 zero4 = {0.f, 0.f, 0.f, 0.f};

    // ---- preload unit 0's zf + mask (rotation seed)
    half8 zf[2][3];
    unsigned long long mw;
    {
        const unsigned short* zl = zh + (size_t)nb * 3072;
        #pragma unroll
        for (int kt = 0; kt < 2; ++kt)
            #pragma unroll
            for (int st = 0; st < 3; ++st)
                zf[kt][st] = *(const half8*)(zl + zoff[kt][st]);
        mw = mask64[nb];
    }

    #pragma unroll 1
    for (int ni = 0; ni < NCH; ++ni) {
        const int n = nb + ni;
        const unsigned short* zt = zhT + (size_t)n * 3584;

        // mask -> additive bias per (st,r): s = 16st+4g+r; 0 or -16384
        f32x4 binit[3];
        #pragma unroll
        for (int st = 0; st < 3; ++st)
            #pragma unroll
            for (int r = 0; r < 4; ++r)
                binit[st][r] = ((mw >> (16 * st + 4 * g + r)) & 1ull) ? 0.f : -16384.f;

        // ---- layer 1: H^T = W1^T x Z^T (b1 enters as kt=0's C-operand)
        f32x4 aH[4][3];
        #pragma unroll
        for (int hm = 0; hm < 4; ++hm)
            #pragma unroll
            for (int st = 0; st < 3; ++st) {
                aH[hm][st] = __builtin_amdgcn_mfma_f32_16x16x32_f16(
                    w1fr[hm * 2 + 0], zf[0][st], b1q[hm], 0, 0, 0);
                aH[hm][st] = __builtin_amdgcn_mfma_f32_16x16x32_f16(
                    w1fr[hm * 2 + 1], zf[1][st], aH[hm][st], 0, 0, 0);
            }

        // ---- rotation: zf consumed -> issue next unit's zf + mask now
        if (ni + 1 < NCH) {
            const unsigned short* zl = zh + (size_t)(n + 1) * 3072;
            #pragma unroll
            for (int kt = 0; kt < 2; ++kt)
                #pragma unroll
                for (int st = 0; st < 3; ++st)
                    zf[kt][st] = *(const half8*)(zl + zoff[kt][st]);
            mw = mask64[n + 1];
        }

        // pack-then-relu: cvt_pkrtz -> packed max with 0 (registers only)
        unsigned int pk[4][3][2];
        #pragma unroll
        for (int hm = 0; hm < 4; ++hm)
            #pragma unroll
            for (int st = 0; st < 3; ++st) {
                UCV a, b;
                a.f = __builtin_elementwise_max(
                    __builtin_amdgcn_cvt_pkrtz(aH[hm][st][0], aH[hm][st][1]), zero2);
                b.f = __builtin_elementwise_max(
                    __builtin_amdgcn_cvt_pkrtz(aH[hm][st][2], aH[hm][st][3]), zero2);
                pk[hm][st][0] = a.i;
                pk[hm][st][1] = b.i;
            }

        // ---- per-jt: L2 MFMA (k-permuted, A lane-local; binit as C) +
        //      exp/pack + ones-MFMA den (no cross-lane) + fdot2 num
        U2 zuc[3], zun[3];
        #pragma unroll
        for (int st = 0; st < 3; ++st)
            zuc[st].u = *(const uint2*)(zt + ztbase + st * 16);
        float part = 0.f;
        #pragma unroll
        for (int jt = 0; jt < 4; ++jt) {
            f32x4 aL3[3];
            #pragma unroll
            for (int st = 0; st < 3; ++st) {
                U8 hfu;
                hfu.w[0] = pk[0][st][0];
                hfu.w[1] = pk[0][st][1];
                hfu.w[2] = pk[1][st][0];
                hfu.w[3] = pk[1][st][1];
                aL3[st] = __builtin_amdgcn_mfma_f32_16x16x32_f16(
                    hfu.v, w2fr[jt * 2 + 0], binit[st], 0, 0, 0);
                hfu.w[0] = pk[2][st][0];
                hfu.w[1] = pk[2][st][1];
                hfu.w[2] = pk[3][st][0];
                hfu.w[3] = pk[3][st][1];
                aL3[st] = __builtin_amdgcn_mfma_f32_16x16x32_f16(
                    hfu.v, w2fr[jt * 2 + 1], aL3[st], 0, 0, 0);
            }
            if (jt < 3) {
                #pragma unroll
                for (int st = 0; st < 3; ++st)
                    zun[st].u = *(const uint2*)(zt + ztbase + (jt + 1) * 896 + st * 16);
            }
            // exp -> packed f16 e-words
            UCV p01[3], p23[3];
            #pragma unroll
            for (int st = 0; st < 3; ++st) {
                float v0 = exp2f(aL3[st][0]), v1 = exp2f(aL3[st][1]);
                float v2 = exp2f(aL3[st][2]), v3 = exp2f(aL3[st][3]);
                p01[st].f = __builtin_amdgcn_cvt_pkrtz(v0, v1);
                p23[st].f = __builtin_amdgcn_cvt_pkrtz(v2, v3);
            }
            // den via ones-MFMA: B-frag = own e-words (k-order irrelevant)
            U8 ef0, ef1;
            ef0.w[0] = p01[0].i; ef0.w[1] = p23[0].i;
            ef0.w[2] = p01[1].i; ef0.w[3] = p23[1].i;
            ef1.w[0] = p01[2].i; ef1.w[1] = p23[2].i;
            ef1.w[2] = 0u;       ef1.w[3] = 0u;
            f32x4 dv = __builtin_amdgcn_mfma_f32_16x16x32_f16(
                ones.v, ef0.v, zero4, 0, 0, 0);
            dv = __builtin_amdgcn_mfma_f32_16x16x32_f16(
                ones.v, ef1.v, dv, 0, 0, 0);
            // num via fdot2 against zT
            float num = 0.f;
            #pragma unroll
            for (int st = 0; st < 3; ++st) {
                UCV z01, z23;
                z01.i = zuc[st].u.x;
                z23.i = zuc[st].u.y;
                num = __builtin_amdgcn_fdot2(p01[st].h, z01.h, num, false);
                num = __builtin_amdgcn_fdot2(p23[st].h, z23.h, num, false);
            }
            part = fmaf(num, __builtin_amdgcn_rcpf(dv[0]), part);
            if (jt < 3) {
                #pragma unroll
                for (int st = 0; st < 3; ++st) zuc[st] = zun[st];
            }
        }
        // ---- DPP 64-lane reduce (VALU only, no DS); total lands in lane 63
        part = wave_sum_dpp(part);
        if (lane == 63) out[n * 128 + d] = part;
    }
}

extern "C" void kernel_launch(void* const* d_in, const int* in_sizes, int n_in,
                              void* d_out, int out_size, void* d_ws, size_t ws_size,
                              hipStream_t stream) {
    const float* values = (const float*)d_in[0];
    const float* times  = (const float*)d_in[1];
    const int*   mask   = (const int*)d_in[2];
    const float* omega  = (const float*)d_in[3];
    const float* alpha  = (const float*)d_in[4];
    const float* W1     = (const float*)d_in[5];
    const float* b1     = (const float*)d_in[6];
    const float* W2     = (const float*)d_in[7];
    // b2 (d_in[8]) cancels in softmax (constant along s). Not read.
    float* out = (float*)d_out;

    unsigned short* zh  = (unsigned short*)d_ws;                 // 786432 f16
    unsigned short* zhT = zh  + (size_t)786432;                  // 917504 f16
    unsigned short* w1f = zhT + (size_t)917504;                  // 520192 f16
    unsigned short* w2f = w1f + (size_t)520192;                  // 520192 f16
    unsigned long long* m64 = (unsigned long long*)(w2f + (size_t)520192);

    prep_k<<<dim3(1214), dim3(256), 0, stream>>>(
        values, times, mask, omega, alpha, W1, W2,
        zh, zhT, w1f, w2f, m64, out);
    filter_k<<<dim3(32, 16), dim3(512), 0, stream>>>(
        zh, zhT, m64, w1f, w2f, b1, out);
}

// Round 20
// 50.810 us; speedup vs baseline: 1.5117x; 1.1545x over previous
//
#include <hip/hip_runtime.h>
#include <math.h>

#define NSEQ 256
#define SLEN 48
#define DIN  64
#define NCH  8
#define LOG2E 1.4426950408889634f

typedef _Float16 half8  __attribute__((ext_vector_type(8)));
typedef __fp16   fp16x2 __attribute__((ext_vector_type(2)));
typedef _Float16 h2t    __attribute__((ext_vector_type(2)));
typedef float    f32x4  __attribute__((ext_vector_type(4)));

union U8  { _Float16 h[8]; uint4 u; unsigned int w[4]; half8 v; };
union U2  { _Float16 h[4]; uint2 u; };
union UCV { fp16x2 f; h2t h; unsigned int i; };
union UFI { float f; int i; };

// DPP 64-lane sum: 6 VALU adds, no DS pipe. Result valid in lane 63.
__device__ __forceinline__ float wave_sum_dpp(float x) {
    UFI v, t;
    v.f = x;
    t.i = __builtin_amdgcn_update_dpp(0, v.i, 0xB1,  0xF, 0xF, true);  // quad_perm [1,0,3,2]
    v.f += t.f;
    t.i = __builtin_amdgcn_update_dpp(0, v.i, 0x4E,  0xF, 0xF, true);  // quad_perm [2,3,0,1]
    v.f += t.f;
    t.i = __builtin_amdgcn_update_dpp(0, v.i, 0x141, 0xF, 0xF, true);  // row_half_mirror
    v.f += t.f;
    t.i = __builtin_amdgcn_update_dpp(0, v.i, 0x140, 0xF, 0xF, true);  // row_mirror
    v.f += t.f;
    t.i = __builtin_amdgcn_update_dpp(0, v.i, 0x142, 0xA, 0xF, false); // row_bcast:15 -> rows 1,3
    v.f += t.f;
    t.i = __builtin_amdgcn_update_dpp(0, v.i, 0x143, 0xC, 0xF, false); // row_bcast:31 -> rows 2,3
    v.f += t.f;
    return v.f;
}

// ---------------- K1: ALL prep fused into one launch ----------------
// blocks 0..126: W1 frag prep | 127..253: W2 frag prep (k-perm pi, *log2e)
// blocks 254..637: embed (zh) | 638..1149: embedT (zhT)
// blocks 1150..1213: mask -> f32 bias table {0,-16384} + out[:,127]
__global__ __launch_bounds__(256) void prep_k(
    const float* __restrict__ values, const float* __restrict__ times,
    const int* __restrict__ mask,
    const float* __restrict__ omega, const float* __restrict__ alpha,
    const float* __restrict__ W1, const float* __restrict__ W2,
    unsigned short* __restrict__ zh, unsigned short* __restrict__ zhT,
    unsigned short* __restrict__ w1f, unsigned short* __restrict__ w2f,
    float* __restrict__ bias, float* __restrict__ out)
{
    const int bid = blockIdx.x;
    if (bid < 254) {
        // ---- weight fragment prep
        const int isW2 = (bid >= 127);
        const float* W = isW2 ? W2 : W1;
        unsigned short* Wf = isW2 ? w2f : w1f;
        const float scale = isW2 ? LOG2E : 1.0f;
        const int d = isW2 ? bid - 127 : bid;
        __shared__ float wl[DIN * DIN];
        const float* src = W + (size_t)d * DIN * DIN;
        for (int k = threadIdx.x; k < DIN * DIN / 4; k += 256)
            ((float4*)wl)[k] = ((const float4*)src)[k];
        __syncthreads();
        for (int rr = 0; rr < 2; ++rr) {
            int idx = threadIdx.x * 2 + rr;
            int fid = idx >> 6, l = idx & 63;
            int mt = fid >> 1, kt = fid & 1, g = l >> 4, c = l & 15;
            U8 t;
            #pragma unroll
            for (int e = 0; e < 8; ++e) {
                int row = isW2 ? (32 * kt + 16 * (e >> 2) + 4 * g + (e & 3))
                               : (32 * kt + 8 * g + e);
                t.h[e] = (_Float16)(wl[row * DIN + (16 * mt + c)] * scale);
            }
            *(uint4*)(Wf + ((size_t)(d * 8 + fid) * 64 + l) * 8) = t.u;
        }
    } else if (bid < 638) {
        // ---- embed: zh[n*s][64], chunk-swizzled
        int id = (bid - 254) * 256 + threadIdx.x;
        int ch = id & 7, ns = id >> 3;
        if (ns >= NSEQ * SLEN) return;
        int s = ns % SLEN;
        float t = times[ns];
        U8 o;
        #pragma unroll
        for (int e = 0; e < 8; ++e) {
            int i = ch * 8 + e;
            float r;
            if (i == 0)       r = omega[0] * t + alpha[0];
            else if (i == 63) r = values[ns];
            else              r = __sinf(t * omega[i] + alpha[i]);
            o.h[e] = (_Float16)r;
        }
        int csw = ch ^ (s & 7);
        *(uint4*)(zh + (size_t)ns * 64 + csw * 8) = o.u;
    } else if (bid < 1150) {
        // ---- embedT: zhT[n][j][s], row stride 56
        int id = (bid - 638) * 256 + threadIdx.x;
        int unit = id & 511, n = id >> 9;
        int sc = unit >> 6;
        if (sc >= 6) return;
        int j = unit & 63;
        int s0 = sc * 8;
        const float* tp = times + n * SLEN + s0;
        float4 t0 = *(const float4*)tp, t1 = *(const float4*)(tp + 4);
        float tv[8] = {t0.x, t0.y, t0.z, t0.w, t1.x, t1.y, t1.z, t1.w};
        U8 o;
        if (j == 0) {
            float om = omega[0], al = alpha[0];
            #pragma unroll
            for (int e = 0; e < 8; ++e) o.h[e] = (_Float16)(om * tv[e] + al);
        } else if (j == 63) {
            const float* vp = values + n * SLEN + s0;
            float4 v0 = *(const float4*)vp, v1 = *(const float4*)(vp + 4);
            float vv[8] = {v0.x, v0.y, v0.z, v0.w, v1.x, v1.y, v1.z, v1.w};
            #pragma unroll
            for (int e = 0; e < 8; ++e) o.h[e] = (_Float16)vv[e];
        } else {
            float om = omega[j], al = alpha[j];
            #pragma unroll
            for (int e = 0; e < 8; ++e) o.h[e] = (_Float16)__sinf(tv[e] * om + al);
        }
        *(uint4*)(zhT + (size_t)n * 3584 + j * 56 + s0) = o.u;
    } else {
        // ---- mask -> bias table {0,-16384} + out[:,127]
        int wid  = ((bid - 1150) * 256 + threadIdx.x) >> 6;   // n
        int lane = threadIdx.x & 63;
        if (wid >= NSEQ) return;
        int mv = (lane < SLEN) ? mask[wid * SLEN + lane] : 0;
        unsigned long long b = __ballot(mv != 0);
        if (lane < SLEN) bias[wid * SLEN + lane] = mv ? 0.f : -16384.f;
        if (lane == 0) out[wid * 128 + 127] = b ? 1.f : 0.f;
    }
}

// ---------------- K4: main fused kernel ----------------
// = r19 (512-thread blocks, launch_bounds(512,2) no-spill, zero LDS/barriers,
// XCD remap, rotated zf prefetch, b1-as-C, pack-relu, ones-MFMA den, fdot2
// num, b2 deleted, DPP reduce) + NEW:
//  (1) mask bias from precomputed f32 table (3 f32x4 loads replace ~28 VALU
//      of 64-bit shifts; VMEM pipe idle, value consumed late -> latency free)
//  (2) zuc/zun pipeline dropped: direct per-jt zt loads, unrolled scheduler
//      hoists them itself (kills 18 reg-movs/unit)
//  (3) exp2f -> __builtin_amdgcn_exp2f (bare v_exp_f32, no ocml wrapper)
__global__ __launch_bounds__(512, 2) void filter_k(
    const unsigned short* __restrict__ zh,
    const unsigned short* __restrict__ zhT,
    const float* __restrict__ bias,
    const unsigned short* __restrict__ w1f, const unsigned short* __restrict__ w2f,
    const float* __restrict__ b1,
    float* __restrict__ out)
{
    const int tid = threadIdx.x;
    const int w = tid >> 6, lane = tid & 63;
    const int g = lane >> 4, c = lane & 15;

    // XCD-aware remap: 512 blocks; xcd = lin%8, slot = lin/8 (0..63)
    const int lin   = blockIdx.y * 32 + blockIdx.x;
    const int xcd   = lin & 7, slot = lin >> 3;
    const int octet = xcd * 2 + (slot & 1);     // 0..15 (2 octets per XCD)
    const int nchk  = slot >> 1;                // 0..31
    const int d = octet * 8 + w;
    if (d >= 127) return;                       // whole-wave exit; no barriers
    const int nb = nchk * NCH;

    // per-d constants (L2-resident, reused across 8 n's)
    half8 w1fr[8], w2fr[8];
    #pragma unroll
    for (int f = 0; f < 8; ++f) {
        w1fr[f] = *(const half8*)(w1f + ((size_t)(d * 8 + f) * 64 + lane) * 8);
        w2fr[f] = *(const half8*)(w2f + ((size_t)(d * 8 + f) * 64 + lane) * 8);
    }
    f32x4 b1q[4];
    #pragma unroll
    for (int hm = 0; hm < 4; ++hm)
        b1q[hm] = *(const f32x4*)(b1 + d * DIN + 16 * hm + 4 * g);

    // hoisted global-address offsets (element units)
    int zoff[2][3];   // b128 frag reads: row s=16st+c, chunk (4kt+g)^(s&7)
    #pragma unroll
    for (int kt = 0; kt < 2; ++kt)
        #pragma unroll
        for (int st = 0; st < 3; ++st) {
            int s = 16 * st + c;
            zoff[kt][st] = s * 64 + (((4 * kt + g) ^ (s & 7)) << 3);
        }
    const int ztbase = c * 56 + 4 * g;   // zT: row j=16jt+c, s=16st+4g

    const fp16x2 zero2 = {(__fp16)0.f, (__fp16)0.f};
    U8 ones;
    #pragma unroll
    for (int e = 0; e < 8; ++e) ones.h[e] = (_Float16)1.f;
    const f32x4 zero4 = {0.f, 0.f, 0.f, 0.f};

    // ---- preload unit 0's zf (rotation seed)
    half8 zf[2][3];
    {
        const unsigned short* zl = zh + (size_t)nb * 3072;
        #pragma unroll
        for (int kt = 0; kt < 2; ++kt)
            #pragma unroll
            for (int st = 0; st < 3; ++st)
                zf[kt][st] = *(const half8*)(zl + zoff[kt][st]);
    }

    #pragma unroll 1
    for (int ni = 0; ni < NCH; ++ni) {
        const int n = nb + ni;
        const unsigned short* zt = zhT + (size_t)n * 3584;

        // mask bias per (st): s = 16st+4g+r, from precomputed f32 table
        const float* bn = bias + n * SLEN;
        f32x4 binit[3];
        #pragma unroll
        for (int st = 0; st < 3; ++st)
            binit[st] = *(const f32x4*)(bn + 16 * st + 4 * g);

        // ---- layer 1: H^T = W1^T x Z^T (b1 enters as kt=0's C-operand)
        f32x4 aH[4][3];
        #pragma unroll
        for (int hm = 0; hm < 4; ++hm)
            #pragma unroll
            for (int st = 0; st < 3; ++st) {
                aH[hm][st] = __builtin_amdgcn_mfma_f32_16x16x32_f16(
                    w1fr[hm * 2 + 0], zf[0][st], b1q[hm], 0, 0, 0);
                aH[hm][st] = __builtin_amdgcn_mfma_f32_16x16x32_f16(
                    w1fr[hm * 2 + 1], zf[1][st], aH[hm][st], 0, 0, 0);
            }

        // ---- rotation: zf consumed -> issue next unit's zf now
        if (ni + 1 < NCH) {
            const unsigned short* zl = zh + (size_t)(n + 1) * 3072;
            #pragma unroll
            for (int kt = 0; kt < 2; ++kt)
                #pragma unroll
                for (int st = 0; st < 3; ++st)
                    zf[kt][st] = *(const half8*)(zl + zoff[kt][st]);
        }

        // pack-then-relu: cvt_pkrtz -> packed max with 0 (registers only)
        unsigned int pk[4][3][2];
        #pragma unroll
        for (int hm = 0; hm < 4; ++hm)
            #pragma unroll
            for (int st = 0; st < 3; ++st) {
                UCV a, b;
                a.f = __builtin_elementwise_max(
                    __builtin_amdgcn_cvt_pkrtz(aH[hm][st][0], aH[hm][st][1]), zero2);
                b.f = __builtin_elementwise_max(
                    __builtin_amdgcn_cvt_pkrtz(aH[hm][st][2], aH[hm][st][3]), zero2);
                pk[hm][st][0] = a.i;
                pk[hm][st][1] = b.i;
            }

        // ---- per-jt: L2 MFMA (k-permuted, A lane-local; binit as C) +
        //      exp/pack + ones-MFMA den (no cross-lane) + fdot2 num
        float part = 0.f;
        #pragma unroll
        for (int jt = 0; jt < 4; ++jt) {
            f32x4 aL3[3];
            #pragma unroll
            for (int st = 0; st < 3; ++st) {
                U8 hfu;
                hfu.w[0] = pk[0][st][0];
                hfu.w[1] = pk[0][st][1];
                hfu.w[2] = pk[1][st][0];
                hfu.w[3] = pk[1][st][1];
                aL3[st] = __builtin_amdgcn_mfma_f32_16x16x32_f16(
                    hfu.v, w2fr[jt * 2 + 0], binit[st], 0, 0, 0);
                hfu.w[0] = pk[2][st][0];
                hfu.w[1] = pk[2][st][1];
                hfu.w[2] = pk[3][st][0];
                hfu.w[3] = pk[3][st][1];
                aL3[st] = __builtin_amdgcn_mfma_f32_16x16x32_f16(
                    hfu.v, w2fr[jt * 2 + 1], aL3[st], 0, 0, 0);
            }
            // exp -> packed f16 e-words (bare v_exp_f32)
            UCV p01[3], p23[3];
            #pragma unroll
            for (int st = 0; st < 3; ++st) {
                float v0 = __builtin_amdgcn_exp2f(aL3[st][0]);
                float v1 = __builtin_amdgcn_exp2f(aL3[st][1]);
                float v2 = __builtin_amdgcn_exp2f(aL3[st][2]);
                float v3 = __builtin_amdgcn_exp2f(aL3[st][3]);
                p01[st].f = __builtin_amdgcn_cvt_pkrtz(v0, v1);
                p23[st].f = __builtin_amdgcn_cvt_pkrtz(v2, v3);
            }
            // den via ones-MFMA: B-frag = own e-words (k-order irrelevant)
            U8 ef0, ef1;
            ef0.w[0] = p01[0].i; ef0.w[1] = p23[0].i;
            ef0.w[2] = p01[1].i; ef0.w[3] = p23[1].i;
            ef1.w[0] = p01[2].i; ef1.w[1] = p23[2].i;
            ef1.w[2] = 0u;       ef1.w[3] = 0u;
            f32x4 dv = __builtin_amdgcn_mfma_f32_16x16x32_f16(
                ones.v, ef0.v, zero4, 0, 0, 0);
            dv = __builtin_amdgcn_mfma_f32_16x16x32_f16(
                ones.v, ef1.v, dv, 0, 0, 0);
            // num via fdot2 against zT (direct loads; scheduler hoists)
            float num = 0.f;
            #pragma unroll
            for (int st = 0; st < 3; ++st) {
                U2 zu;
                zu.u = *(const uint2*)(zt + ztbase + jt * 896 + st * 16);
                UCV z01, z23;
                z01.i = zu.u.x;
                z23.i = zu.u.y;
                num = __builtin_amdgcn_fdot2(p01[st].h, z01.h, num, false);
                num = __builtin_amdgcn_fdot2(p23[st].h, z23.h, num, false);
            }
            part = fmaf(num, __builtin_amdgcn_rcpf(dv[0]), part);
        }
        // ---- DPP 64-lane reduce (VALU only, no DS); total lands in lane 63
        part = wave_sum_dpp(part);
        if (lane == 63) out[n * 128 + d] = part;
    }
}

extern "C" void kernel_launch(void* const* d_in, const int* in_sizes, int n_in,
                              void* d_out, int out_size, void* d_ws, size_t ws_size,
                              hipStream_t stream) {
    const float* values = (const float*)d_in[0];
    const float* times  = (const float*)d_in[1];
    const int*   mask   = (const int*)d_in[2];
    const float* omega  = (const float*)d_in[3];
    const float* alpha  = (const float*)d_in[4];
    const float* W1     = (const float*)d_in[5];
    const float* b1     = (const float*)d_in[6];
    const float* W2     = (const float*)d_in[7];
    // b2 (d_in[8]) cancels in softmax (constant along s). Not read.
    float* out = (float*)d_out;

    unsigned short* zh  = (unsigned short*)d_ws;                 // 786432 f16
    unsigned short* zhT = zh  + (size_t)786432;                  // 917504 f16
    unsigned short* w1f = zhT + (size_t)917504;                  // 520192 f16
    unsigned short* w2f = w1f + (size_t)520192;                  // 520192 f16
    float* bias = (float*)(w2f + (size_t)520192);                // 12288 f32

    prep_k<<<dim3(1214), dim3(256), 0, stream>>>(
        values, times, mask, omega, alpha, W1, W2,
        zh, zhT, w1f, w2f, bias, out);
    filter_k<<<dim3(32, 16), dim3(512), 0, stream>>>(
        zh, zhT, bias, w1f, w2f, b1, out);
}